// Round 4
// baseline (382.285 us; speedup 1.0000x reference)
//
#include <hip/hip_runtime.h>

// Problem constants
#define BB 4
#define LL 2048
#define DD 1024
#define NH 16
#define DH 64
#define MM (BB*LL)   // 8192 rows

typedef _Float16 half8 __attribute__((ext_vector_type(8)));
typedef _Float16 half4 __attribute__((ext_vector_type(4)));
typedef _Float16 half2 __attribute__((ext_vector_type(2)));
typedef float floatx4 __attribute__((ext_vector_type(4)));
typedef float floatx16 __attribute__((ext_vector_type(16)));
typedef unsigned uint4v __attribute__((ext_vector_type(4)));

__device__ __forceinline__ void gload_lds16(const void* g, void* l) {
    __builtin_amdgcn_global_load_lds((const __attribute__((address_space(1))) void*)g,
                                     (__attribute__((address_space(3))) void*)l,
                                     16, 0, 0);
}

__device__ __forceinline__ floatx4 mfma16(half8 a, half8 b, floatx4 c) {
    return __builtin_amdgcn_mfma_f32_16x16x32_f16(a, b, c, 0, 0, 0);
}

__device__ __forceinline__ floatx16 mfma32(half8 a, half8 b, floatx16 c) {
    return __builtin_amdgcn_mfma_f32_32x32x16_f16(a, b, c, 0, 0, 0);
}

__device__ __forceinline__ unsigned pkh(float a, float b) {
    return __builtin_bit_cast(unsigned, __builtin_amdgcn_cvt_pkrtz(a, b));
}

// ---------------- fused fp32 -> fp16 convert (all 7 tensors, 1 launch) ----------------
__global__ __launch_bounds__(256) void cvt_all(const float* __restrict__ q,
                                               const float* __restrict__ k,
                                               const float* __restrict__ v,
                                               const float* __restrict__ Wq,
                                               const float* __restrict__ Wk,
                                               const float* __restrict__ Wv,
                                               const float* __restrict__ Wo,
                                               _Float16* __restrict__ dst) {
    const int BIG = 8192;    // blocks per big tensor (8.39M elems / 1024)
    const int SML = 1024;    // blocks per weight tensor
    const size_t NQKV = (size_t)MM * DD;
    const size_t NW = (size_t)DD * DD;
    int b = blockIdx.x;
    const float* src;
    size_t off;
    int lb;
    if (b < 3 * BIG) {
        int t = b / BIG;
        src = t == 0 ? q : (t == 1 ? k : v);
        off = (size_t)t * NQKV;
        lb = b - t * BIG;
    } else {
        int t = (b - 3 * BIG) / SML;
        src = t == 0 ? Wq : (t == 1 ? Wk : (t == 2 ? Wv : Wo));
        off = 3 * NQKV + (size_t)t * NW;
        lb = b - 3 * BIG - t * SML;
    }
    size_t i = (size_t)lb * 256 + threadIdx.x;
    float4 f = ((const float4*)src)[i];
    half4 h;
    h[0] = (_Float16)f.x; h[1] = (_Float16)f.y;
    h[2] = (_Float16)f.z; h[3] = (_Float16)f.w;
    ((half4*)(dst + off))[i] = h;
}

// ---------------- fused QKV projection GEMM ----------------
__global__ __launch_bounds__(256) void gemm_qkv(const _Float16* __restrict__ qkv16,
                                                const _Float16* __restrict__ wq,
                                                const _Float16* __restrict__ wk,
                                                const _Float16* __restrict__ wv,
                                                const float* __restrict__ bq,
                                                const float* __restrict__ bk,
                                                const float* __restrict__ bv,
                                                _Float16* __restrict__ Qp,
                                                _Float16* __restrict__ Kp,
                                                _Float16* __restrict__ VtG) {
    const int K = 1024;
    __shared__ _Float16 As[128 * 32];
    __shared__ _Float16 Bs[128 * 32];

    int tid = threadIdx.x;
    int wave = tid >> 6, lane = tid & 63;
    int quad = lane >> 4, l15 = lane & 15;
    int wrow = (wave >> 1) * 64, wcol = (wave & 1) * 64;
    int bx = blockIdx.x;
    int which = bx >> 3;  // 0=Q, 1=K, 2=V
    int m0 = blockIdx.y * 128;
    int n0 = (bx & 7) * 128;

    const _Float16* A = qkv16 + (size_t)which * ((size_t)MM * DD);  // q16/k16/v16
    const _Float16* W = which == 0 ? wq : (which == 1 ? wk : wv);
    const float* bias = which == 0 ? bq : (which == 1 ? bk : bv);

    floatx4 acc[4][4] = {};

    int srow = tid >> 2, sseg = tid & 3;
    const _Float16* Ag0 = A + (size_t)(m0 + srow) * K + sseg * 8;
    const _Float16* Ag1 = Ag0 + (size_t)64 * K;
    const _Float16* Bg0 = W + (size_t)(n0 + srow) * K + sseg * 8;
    const _Float16* Bg1 = Bg0 + (size_t)64 * K;
    char* ldsA0 = (char*)As + tid * 16;
    char* ldsA1 = (char*)As + (256 + tid) * 16;
    char* ldsB0 = (char*)Bs + tid * 16;
    char* ldsB1 = (char*)Bs + (256 + tid) * 16;

    for (int kt = 0; kt < K; kt += 32) {
        __syncthreads();
        gload_lds16(Ag0 + kt, ldsA0);
        gload_lds16(Ag1 + kt, ldsA1);
        gload_lds16(Bg0 + kt, ldsB0);
        gload_lds16(Bg1 + kt, ldsB1);
        __syncthreads();

        half8 af[4], bf[4];
#pragma unroll
        for (int i = 0; i < 4; i++)
            af[i] = *(half8*)&As[(wrow + i * 16 + l15) * 32 + quad * 8];
#pragma unroll
        for (int j = 0; j < 4; j++)
            bf[j] = *(half8*)&Bs[(wcol + j * 16 + l15) * 32 + quad * 8];
#pragma unroll
        for (int i = 0; i < 4; i++)
#pragma unroll
            for (int j = 0; j < 4; j++)
                acc[i][j] = mfma16(af[i], bf[j], acc[i][j]);
    }

    // add bias (per output col j)
#pragma unroll
    for (int j = 0; j < 4; j++) {
        float bv_ = bias[n0 + wcol + j * 16 + l15];
#pragma unroll
        for (int i = 0; i < 4; i++)
#pragma unroll
            for (int r = 0; r < 4; r++) acc[i][j][r] += bv_;
    }

    if (which < 2) {
        // ---- fused L2 norm: wave's 64-col group == one head ----
        _Float16* C = which == 0 ? Qp : Kp;
#pragma unroll
        for (int i = 0; i < 4; i++) {
#pragma unroll
            for (int r = 0; r < 4; r++) {
                float s = 0.f;
#pragma unroll
                for (int j = 0; j < 4; j++) s += acc[i][j][r] * acc[i][j][r];
                s += __shfl_xor(s, 1);
                s += __shfl_xor(s, 2);
                s += __shfl_xor(s, 4);
                s += __shfl_xor(s, 8);
                float inv = 1.0f / fmaxf(sqrtf(s), 1e-12f);
                int row = m0 + wrow + i * 16 + quad * 4 + r;
#pragma unroll
                for (int j = 0; j < 4; j++) {
                    int col = n0 + wcol + j * 16 + l15;
                    C[(size_t)row * DD + col] = (_Float16)(acc[i][j][r] * inv);
                }
            }
        }
    } else {
        // ---- V: transposed per-head store  VtG[(b*16+h)*64+dh][l] ----
#pragma unroll
        for (int j = 0; j < 4; j++) {
            int col = n0 + wcol + j * 16 + l15;  // h*64+dh
#pragma unroll
            for (int i = 0; i < 4; i++) {
#pragma unroll
                for (int r = 0; r < 4; r++) {
                    int row = m0 + wrow + i * 16 + quad * 4 + r;  // b*2048 + l
                    int b = row >> 11, l = row & 2047;
                    VtG[((size_t)((b << 10) + col)) * LL + l] = (_Float16)acc[i][j][r];
                }
            }
        }
    }
}

// ---------------- output projection GEMM (fp32 out) ----------------
__global__ __launch_bounds__(256) void gemm_out(const _Float16* __restrict__ A,
                                                const _Float16* __restrict__ W,
                                                const float* __restrict__ bias,
                                                float* __restrict__ C) {
    const int K = 1024, N = 1024;
    __shared__ _Float16 As[128 * 32];
    __shared__ _Float16 Bs[128 * 32];

    int tid = threadIdx.x;
    int wave = tid >> 6, lane = tid & 63;
    int quad = lane >> 4, l15 = lane & 15;
    int wrow = (wave >> 1) * 64, wcol = (wave & 1) * 64;
    int m0 = blockIdx.y * 128;
    int n0 = blockIdx.x * 128;

    floatx4 acc[4][4] = {};

    int srow = tid >> 2, sseg = tid & 3;
    const _Float16* Ag0 = A + (size_t)(m0 + srow) * K + sseg * 8;
    const _Float16* Ag1 = Ag0 + (size_t)64 * K;
    const _Float16* Bg0 = W + (size_t)(n0 + srow) * K + sseg * 8;
    const _Float16* Bg1 = Bg0 + (size_t)64 * K;
    char* ldsA0 = (char*)As + tid * 16;
    char* ldsA1 = (char*)As + (256 + tid) * 16;
    char* ldsB0 = (char*)Bs + tid * 16;
    char* ldsB1 = (char*)Bs + (256 + tid) * 16;

    for (int kt = 0; kt < K; kt += 32) {
        __syncthreads();
        gload_lds16(Ag0 + kt, ldsA0);
        gload_lds16(Ag1 + kt, ldsA1);
        gload_lds16(Bg0 + kt, ldsB0);
        gload_lds16(Bg1 + kt, ldsB1);
        __syncthreads();

        half8 af[4], bf[4];
#pragma unroll
        for (int i = 0; i < 4; i++)
            af[i] = *(half8*)&As[(wrow + i * 16 + l15) * 32 + quad * 8];
#pragma unroll
        for (int j = 0; j < 4; j++)
            bf[j] = *(half8*)&Bs[(wcol + j * 16 + l15) * 32 + quad * 8];
#pragma unroll
        for (int i = 0; i < 4; i++)
#pragma unroll
            for (int j = 0; j < 4; j++)
                acc[i][j] = mfma16(af[i], bf[j], acc[i][j]);
    }

#pragma unroll
    for (int j = 0; j < 4; j++) {
        int col = n0 + wcol + j * 16 + l15;
        float bv = bias[col];
#pragma unroll
        for (int i = 0; i < 4; i++) {
#pragma unroll
            for (int r = 0; r < 4; r++) {
                int row = m0 + wrow + i * 16 + quad * 4 + r;
                C[(size_t)row * N + col] = acc[i][j][r] + bv;
            }
        }
    }
}

// ---------------- fused cosine attention (32x32 MFMA, pipelined softmax/PV overlap) -----
// grid: (L/128, B*H). 256 thr = 4 waves; wave w owns queries w*32..w*32+31.
// Swapped QK^T: st = mfma32(Kfrag, Qfrag) -> lane holds scores for q = lane&31.
// Within-wave pipeline: QK0+QK1 issued back-to-back (independent accumulators keep
// the MFMA pipe busy over each other's latency); softmax(c) on VALU overlaps PV(c-1)
// on the matrix pipe (MFMA retires async; VALU issues continue past it).
__global__ __launch_bounds__(256, 4) void attn_k(const _Float16* __restrict__ Q,
                                                 const _Float16* __restrict__ K,
                                                 const _Float16* __restrict__ VtG,
                                                 _Float16* __restrict__ Mg) {
    __shared__ _Float16 Ks[2][64 * 64];
    __shared__ _Float16 Vt[2][64 * 64];
    __shared__ float lsum[128];

    const float C2 = 20.60992915555662f;  // log2(e)/0.07
    const float OFF = 6.0f;

    int tid = threadIdx.x, wave = tid >> 6, lane = tid & 63;
    int l31 = lane & 31, hi = lane >> 5;
    int bh = blockIdx.y;
    int b = bh >> 4, h = bh & 15;
    int q0 = blockIdx.x * 128;
    size_t rowBase = (size_t)b * LL;
    int colBase = h * 64;
    int wq = wave * 32;
    int xorv = l31 & 7;

    // ---- Q fragments: row = q = l31, dh = d*16 + hi*8 + j (held whole kernel)
    half8 qf[4];
    const _Float16* qp = Q + (rowBase + q0 + wq + l31) * DD + colBase + hi * 8;
#pragma unroll
    for (int d = 0; d < 4; d++) qf[d] = *(const half8*)(qp + d * 16);

    // ---- staging: linear LDS dest, pre-swizzled global source (chunk ^= row&7)
    const _Float16* kg[2];
    const _Float16* vg[2];
    int ldso[2];
#pragma unroll
    for (int p = 0; p < 2; p++) {
        int s = p * 256 + tid;
        int r = s >> 3, cp = s & 7;
        int cs = cp ^ (r & 7);
        kg[p] = K + (rowBase + r) * DD + colBase + cs * 8;
        vg[p] = VtG + ((size_t)bh * 64 + r) * LL + cs * 8;
        ldso[p] = s * 16;
    }

    floatx16 oacc[2] = {};
    float fsum = 0.f;

    // prologue: stage tile 0 into buf 0
    gload_lds16(kg[0], (char*)Ks[0] + ldso[0]);
    gload_lds16(kg[1], (char*)Ks[0] + ldso[1]);
    gload_lds16(vg[0], (char*)Vt[0] + ldso[0]);
    gload_lds16(vg[1], (char*)Vt[0] + ldso[1]);
    kg[0] += 64 * DD; kg[1] += 64 * DD; vg[0] += 64; vg[1] += 64;
    __syncthreads();

#pragma unroll 2
    for (int kt = 0; kt < LL / 64; kt++) {
        int cur = kt & 1;
        // prefetch next tile into other buffer (flies during compute below)
        if (kt + 1 < LL / 64) {
            gload_lds16(kg[0], (char*)Ks[cur ^ 1] + ldso[0]);
            gload_lds16(kg[1], (char*)Ks[cur ^ 1] + ldso[1]);
            gload_lds16(vg[0], (char*)Vt[cur ^ 1] + ldso[0]);
            gload_lds16(vg[1], (char*)Vt[cur ^ 1] + ldso[1]);
            kg[0] += 64 * DD; kg[1] += 64 * DD; vg[0] += 64; vg[1] += 64;
        }
        const char* kb_ = (const char*)Ks[cur];
        const char* vb_ = (const char*)Vt[cur];

        // ---- QK^T for BOTH 32-k sub-blocks, back-to-back (8 MFMA, 2 indep chains)
        half8 kf0[4], kf1[4];
#pragma unroll
        for (int d = 0; d < 4; d++) {
            int ch = ((d * 2 + hi) ^ xorv) * 16;
            kf0[d] = *(const half8*)(kb_ + l31 * 128 + ch);
            kf1[d] = *(const half8*)(kb_ + 4096 + l31 * 128 + ch);
        }
        floatx16 st0 = {}, st1 = {};
        __builtin_amdgcn_s_setprio(1);
#pragma unroll
        for (int d = 0; d < 4; d++) st0 = mfma32(kf0[d], qf[d], st0);
#pragma unroll
        for (int d = 0; d < 4; d++) st1 = mfma32(kf1[d], qf[d], st1);
        __builtin_amdgcn_s_setprio(0);

        // ---- softmax block 0 (VALU; overlaps tail of QK1 latency)
        float e0[16];
#pragma unroll
        for (int r = 0; r < 16; r++)
            e0[r] = __builtin_amdgcn_exp2f(st0[r] * C2 - OFF);
        {
            float s0 = (e0[0] + e0[1]) + (e0[2] + e0[3]);
            float s1 = (e0[4] + e0[5]) + (e0[6] + e0[7]);
            float s2 = (e0[8] + e0[9]) + (e0[10] + e0[11]);
            float s3 = (e0[12] + e0[13]) + (e0[14] + e0[15]);
            fsum += (s0 + s1) + (s2 + s3);
        }
        half8 pf0[2];
#pragma unroll
        for (int sl = 0; sl < 2; sl++) {
            int bse = sl * 8;
            unsigned a = pkh(e0[bse + 0], e0[bse + 1]);
            unsigned cc = pkh(e0[bse + 2], e0[bse + 3]);
            unsigned bb = pkh(e0[bse + 4], e0[bse + 5]);
            unsigned dd = pkh(e0[bse + 6], e0[bse + 7]);
            auto r1 = __builtin_amdgcn_permlane32_swap(a, bb, false, false);
            auto r2 = __builtin_amdgcn_permlane32_swap(cc, dd, false, false);
            uint4v u;
            u[0] = (unsigned)r1[0]; u[1] = (unsigned)r2[0];
            u[2] = (unsigned)r1[1]; u[3] = (unsigned)r2[1];
            pf0[sl] = __builtin_bit_cast(half8, u);
        }

        // ---- PV block 0 issued on matrix pipe...
        half8 vf0[2][2];
#pragma unroll
        for (int jb = 0; jb < 2; jb++)
#pragma unroll
            for (int sl = 0; sl < 2; sl++)
                vf0[jb][sl] = *(const half8*)(vb_ + jb * 4096 + l31 * 128 +
                                              (((sl * 2 + hi) ^ xorv) * 16));
        __builtin_amdgcn_s_setprio(1);
#pragma unroll
        for (int jb = 0; jb < 2; jb++)
#pragma unroll
            for (int sl = 0; sl < 2; sl++)
                oacc[jb] = mfma32(pf0[sl], vf0[jb][sl], oacc[jb]);
        __builtin_amdgcn_s_setprio(0);

        // ---- ...while softmax block 1 issues on VALU (no dependency on PV0)
        float e1[16];
#pragma unroll
        for (int r = 0; r < 16; r++)
            e1[r] = __builtin_amdgcn_exp2f(st1[r] * C2 - OFF);
        {
            float s0 = (e1[0] + e1[1]) + (e1[2] + e1[3]);
            float s1 = (e1[4] + e1[5]) + (e1[6] + e1[7]);
            float s2 = (e1[8] + e1[9]) + (e1[10] + e1[11]);
            float s3 = (e1[12] + e1[13]) + (e1[14] + e1[15]);
            fsum += (s0 + s1) + (s2 + s3);
        }
        half8 pf1[2];
#pragma unroll
        for (int sl = 0; sl < 2; sl++) {
            int bse = sl * 8;
            unsigned a = pkh(e1[bse + 0], e1[bse + 1]);
            unsigned cc = pkh(e1[bse + 2], e1[bse + 3]);
            unsigned bb = pkh(e1[bse + 4], e1[bse + 5]);
            unsigned dd = pkh(e1[bse + 6], e1[bse + 7]);
            auto r1 = __builtin_amdgcn_permlane32_swap(a, bb, false, false);
            auto r2 = __builtin_amdgcn_permlane32_swap(cc, dd, false, false);
            uint4v u;
            u[0] = (unsigned)r1[0]; u[1] = (unsigned)r2[0];
            u[2] = (unsigned)r1[1]; u[3] = (unsigned)r2[1];
            pf1[sl] = __builtin_bit_cast(half8, u);
        }

        // ---- PV block 1
        half8 vf1[2][2];
#pragma unroll
        for (int jb = 0; jb < 2; jb++)
#pragma unroll
            for (int sl = 0; sl < 2; sl++)
                vf1[jb][sl] = *(const half8*)(vb_ + jb * 4096 + l31 * 128 +
                                              (((4 + sl * 2 + hi) ^ xorv) * 16));
        __builtin_amdgcn_s_setprio(1);
#pragma unroll
        for (int jb = 0; jb < 2; jb++)
#pragma unroll
            for (int sl = 0; sl < 2; sl++)
                oacc[jb] = mfma32(pf1[sl], vf1[jb][sl], oacc[jb]);
        __builtin_amdgcn_s_setprio(0);

        __syncthreads();  // drains vmcnt -> next buffer ready
    }

    // ---- epilogue: combine hi-halves of row sums, normalize, store
    fsum += __shfl_xor(fsum, 32);
    lsum[wq + l31] = fsum;
    __syncthreads();

    _Float16* mp = Mg + (rowBase + q0 + wq) * DD + colBase + l31;
#pragma unroll
    for (int jb = 0; jb < 2; jb++) {
#pragma unroll
        for (int r = 0; r < 16; r++) {
            int crow = (r & 3) + 8 * (r >> 2) + 4 * hi;
            float inv = 1.0f / lsum[wq + crow];
            mp[(size_t)crow * DD + jb * 32] = (_Float16)(oacc[jb][r] * inv);
        }
    }
}

// ---------------- launch ----------------
extern "C" void kernel_launch(void* const* d_in, const int* in_sizes, int n_in,
                              void* d_out, int out_size, void* d_ws, size_t ws_size,
                              hipStream_t stream) {
    (void)in_sizes; (void)n_in; (void)out_size; (void)ws_size;
    const float* q  = (const float*)d_in[0];
    const float* k  = (const float*)d_in[1];
    const float* v  = (const float*)d_in[2];
    const float* Wq = (const float*)d_in[3];
    const float* bq = (const float*)d_in[4];
    const float* Wk = (const float*)d_in[5];
    const float* bk = (const float*)d_in[6];
    const float* Wv = (const float*)d_in[7];
    const float* bv = (const float*)d_in[8];
    const float* Wo = (const float*)d_in[9];
    const float* bo = (const float*)d_in[10];

    const size_t NQKV = (size_t)MM * DD;  // 8388608
    const size_t NW = (size_t)DD * DD;    // 1048576

    _Float16* q16  = (_Float16*)d_ws;
    _Float16* k16  = q16 + NQKV;
    _Float16* v16  = k16 + NQKV;
    _Float16* wq16 = v16 + NQKV;
    _Float16* wk16 = wq16 + NW;
    _Float16* wv16 = wk16 + NW;
    _Float16* wo16 = wv16 + NW;
    _Float16* Qp   = wo16 + NW;
    _Float16* Kp   = Qp + NQKV;
    _Float16* VtG  = Kp + NQKV;
    _Float16* Mg   = VtG + NQKV;
    (void)k16; (void)v16;

    // one fused convert: 3*8192 + 4*1024 blocks
    cvt_all<<<dim3(3 * 8192 + 4 * 1024), dim3(256), 0, stream>>>(q, k, v, Wq, Wk, Wv, Wo, q16);

    // fused QKV projection (+l2norm on Q/K, transposed V); A = q16/k16/v16 by block
    gemm_qkv<<<dim3(24, MM / 128), dim3(256), 0, stream>>>(q16, wq16, wk16, wv16,
                                                           bq, bk, bv, Qp, Kp, VtG);

    // fused attention
    attn_k<<<dim3(LL / 128, BB * NH), dim3(256), 0, stream>>>(Qp, Kp, VtG, Mg);

    // output projection -> fp32 d_out
    gemm_out<<<dim3(1024 / 128, MM / 128), dim3(256), 0, stream>>>(Mg, wo16, bo, (float*)d_out);
}

// Round 5
// 370.816 us; speedup vs baseline: 1.0309x; 1.0309x over previous
//
#include <hip/hip_runtime.h>

// Problem constants
#define BB 4
#define LL 2048
#define DD 1024
#define NH 16
#define DH 64
#define MM (BB*LL)   // 8192 rows

typedef _Float16 half8 __attribute__((ext_vector_type(8)));
typedef _Float16 half4 __attribute__((ext_vector_type(4)));
typedef _Float16 half2 __attribute__((ext_vector_type(2)));
typedef float floatx4 __attribute__((ext_vector_type(4)));
typedef float floatx16 __attribute__((ext_vector_type(16)));
typedef unsigned uint4v __attribute__((ext_vector_type(4)));

__device__ __forceinline__ void gload_lds16(const void* g, void* l) {
    __builtin_amdgcn_global_load_lds((const __attribute__((address_space(1))) void*)g,
                                     (__attribute__((address_space(3))) void*)l,
                                     16, 0, 0);
}

__device__ __forceinline__ floatx4 mfma16(half8 a, half8 b, floatx4 c) {
    return __builtin_amdgcn_mfma_f32_16x16x32_f16(a, b, c, 0, 0, 0);
}

__device__ __forceinline__ floatx16 mfma32(half8 a, half8 b, floatx16 c) {
    return __builtin_amdgcn_mfma_f32_32x32x16_f16(a, b, c, 0, 0, 0);
}

__device__ __forceinline__ unsigned pkh(float a, float b) {
    return __builtin_bit_cast(unsigned, __builtin_amdgcn_cvt_pkrtz(a, b));
}

// ---------------- fused fp32 -> fp16 convert (all 7 tensors, 1 launch) ----------------
__global__ __launch_bounds__(256) void cvt_all(const float* __restrict__ q,
                                               const float* __restrict__ k,
                                               const float* __restrict__ v,
                                               const float* __restrict__ Wq,
                                               const float* __restrict__ Wk,
                                               const float* __restrict__ Wv,
                                               const float* __restrict__ Wo,
                                               _Float16* __restrict__ dst) {
    const int BIG = 8192;    // blocks per big tensor (8.39M elems / 1024)
    const int SML = 1024;    // blocks per weight tensor
    const size_t NQKV = (size_t)MM * DD;
    const size_t NW = (size_t)DD * DD;
    int b = blockIdx.x;
    const float* src;
    size_t off;
    int lb;
    if (b < 3 * BIG) {
        int t = b / BIG;
        src = t == 0 ? q : (t == 1 ? k : v);
        off = (size_t)t * NQKV;
        lb = b - t * BIG;
    } else {
        int t = (b - 3 * BIG) / SML;
        src = t == 0 ? Wq : (t == 1 ? Wk : (t == 2 ? Wv : Wo));
        off = 3 * NQKV + (size_t)t * NW;
        lb = b - 3 * BIG - t * SML;
    }
    size_t i = (size_t)lb * 256 + threadIdx.x;
    float4 f = ((const float4*)src)[i];
    half4 h;
    h[0] = (_Float16)f.x; h[1] = (_Float16)f.y;
    h[2] = (_Float16)f.z; h[3] = (_Float16)f.w;
    ((half4*)(dst + off))[i] = h;
}

// ---------------- fused QKV projection GEMM (2-phase double-buffered) ----------------
// grid (24, 64): bx 0..7 -> Q (+l2norm), 8..15 -> K (+l2norm), 16..23 -> V (transposed)
// K-step t+1 staged into buf^1 while computing buf; ONE barrier per K-step.
__global__ __launch_bounds__(256) void gemm_qkv(const _Float16* __restrict__ qkv16,
                                                const _Float16* __restrict__ wq,
                                                const _Float16* __restrict__ wk,
                                                const _Float16* __restrict__ wv,
                                                const float* __restrict__ bq,
                                                const float* __restrict__ bk,
                                                const float* __restrict__ bv,
                                                _Float16* __restrict__ Qp,
                                                _Float16* __restrict__ Kp,
                                                _Float16* __restrict__ VtG) {
    const int K = 1024;
    __shared__ _Float16 As[2][128 * 32];
    __shared__ _Float16 Bs[2][128 * 32];

    int tid = threadIdx.x;
    int wave = tid >> 6, lane = tid & 63;
    int quad = lane >> 4, l15 = lane & 15;
    int wrow = (wave >> 1) * 64, wcol = (wave & 1) * 64;
    int bx = blockIdx.x;
    int which = bx >> 3;  // 0=Q, 1=K, 2=V
    int m0 = blockIdx.y * 128;
    int n0 = (bx & 7) * 128;

    const _Float16* A = qkv16 + (size_t)which * ((size_t)MM * DD);  // q16/k16/v16
    const _Float16* W = which == 0 ? wq : (which == 1 ? wk : wv);
    const float* bias = which == 0 ? bq : (which == 1 ? bk : bv);

    floatx4 acc[4][4] = {};

    int srow = tid >> 2, sseg = tid & 3;
    const _Float16* Ag0 = A + (size_t)(m0 + srow) * K + sseg * 8;
    const _Float16* Ag1 = Ag0 + (size_t)64 * K;
    const _Float16* Bg0 = W + (size_t)(n0 + srow) * K + sseg * 8;
    const _Float16* Bg1 = Bg0 + (size_t)64 * K;
    int lo0 = tid * 16, lo1 = (256 + tid) * 16;

    // prologue: stage kt=0 into buf 0
    gload_lds16(Ag0, (char*)As[0] + lo0);
    gload_lds16(Ag1, (char*)As[0] + lo1);
    gload_lds16(Bg0, (char*)Bs[0] + lo0);
    gload_lds16(Bg1, (char*)Bs[0] + lo1);
    __syncthreads();

    for (int kt = 0; kt < K; kt += 32) {
        int cur = (kt >> 5) & 1;
        // prefetch next K-step into other buffer (flies under the MFMAs)
        if (kt + 32 < K) {
            gload_lds16(Ag0 + kt + 32, (char*)As[cur ^ 1] + lo0);
            gload_lds16(Ag1 + kt + 32, (char*)As[cur ^ 1] + lo1);
            gload_lds16(Bg0 + kt + 32, (char*)Bs[cur ^ 1] + lo0);
            gload_lds16(Bg1 + kt + 32, (char*)Bs[cur ^ 1] + lo1);
        }

        half8 af[4], bf[4];
#pragma unroll
        for (int i = 0; i < 4; i++)
            af[i] = *(half8*)&As[cur][(wrow + i * 16 + l15) * 32 + quad * 8];
#pragma unroll
        for (int j = 0; j < 4; j++)
            bf[j] = *(half8*)&Bs[cur][(wcol + j * 16 + l15) * 32 + quad * 8];
#pragma unroll
        for (int i = 0; i < 4; i++)
#pragma unroll
            for (int j = 0; j < 4; j++)
                acc[i][j] = mfma16(af[i], bf[j], acc[i][j]);

        __syncthreads();  // drains vmcnt -> prefetched buffer ready; buf[cur] safe to overwrite
    }

    // add bias (per output col j)
#pragma unroll
    for (int j = 0; j < 4; j++) {
        float bv_ = bias[n0 + wcol + j * 16 + l15];
#pragma unroll
        for (int i = 0; i < 4; i++)
#pragma unroll
            for (int r = 0; r < 4; r++) acc[i][j][r] += bv_;
    }

    if (which < 2) {
        // ---- fused L2 norm: wave's 64-col group == one head ----
        _Float16* C = which == 0 ? Qp : Kp;
#pragma unroll
        for (int i = 0; i < 4; i++) {
#pragma unroll
            for (int r = 0; r < 4; r++) {
                float s = 0.f;
#pragma unroll
                for (int j = 0; j < 4; j++) s += acc[i][j][r] * acc[i][j][r];
                s += __shfl_xor(s, 1);
                s += __shfl_xor(s, 2);
                s += __shfl_xor(s, 4);
                s += __shfl_xor(s, 8);
                float inv = 1.0f / fmaxf(sqrtf(s), 1e-12f);
                int row = m0 + wrow + i * 16 + quad * 4 + r;
#pragma unroll
                for (int j = 0; j < 4; j++) {
                    int col = n0 + wcol + j * 16 + l15;
                    C[(size_t)row * DD + col] = (_Float16)(acc[i][j][r] * inv);
                }
            }
        }
    } else {
        // ---- V: transposed per-head store  VtG[(b*16+h)*64+dh][l] ----
#pragma unroll
        for (int j = 0; j < 4; j++) {
            int col = n0 + wcol + j * 16 + l15;  // h*64+dh
#pragma unroll
            for (int i = 0; i < 4; i++) {
#pragma unroll
                for (int r = 0; r < 4; r++) {
                    int row = m0 + wrow + i * 16 + quad * 4 + r;  // b*2048 + l
                    int b = row >> 11, l = row & 2047;
                    VtG[((size_t)((b << 10) + col)) * LL + l] = (_Float16)acc[i][j][r];
                }
            }
        }
    }
}

// ---------------- output projection GEMM (2-phase double-buffered, fp32 out) ----------
__global__ __launch_bounds__(256) void gemm_out(const _Float16* __restrict__ A,
                                                const _Float16* __restrict__ W,
                                                const float* __restrict__ bias,
                                                float* __restrict__ C) {
    const int K = 1024, N = 1024;
    __shared__ _Float16 As[2][128 * 32];
    __shared__ _Float16 Bs[2][128 * 32];

    int tid = threadIdx.x;
    int wave = tid >> 6, lane = tid & 63;
    int quad = lane >> 4, l15 = lane & 15;
    int wrow = (wave >> 1) * 64, wcol = (wave & 1) * 64;
    int m0 = blockIdx.y * 128;
    int n0 = blockIdx.x * 128;

    floatx4 acc[4][4] = {};

    int srow = tid >> 2, sseg = tid & 3;
    const _Float16* Ag0 = A + (size_t)(m0 + srow) * K + sseg * 8;
    const _Float16* Ag1 = Ag0 + (size_t)64 * K;
    const _Float16* Bg0 = W + (size_t)(n0 + srow) * K + sseg * 8;
    const _Float16* Bg1 = Bg0 + (size_t)64 * K;
    int lo0 = tid * 16, lo1 = (256 + tid) * 16;

    // prologue: stage kt=0 into buf 0
    gload_lds16(Ag0, (char*)As[0] + lo0);
    gload_lds16(Ag1, (char*)As[0] + lo1);
    gload_lds16(Bg0, (char*)Bs[0] + lo0);
    gload_lds16(Bg1, (char*)Bs[0] + lo1);
    __syncthreads();

    for (int kt = 0; kt < K; kt += 32) {
        int cur = (kt >> 5) & 1;
        if (kt + 32 < K) {
            gload_lds16(Ag0 + kt + 32, (char*)As[cur ^ 1] + lo0);
            gload_lds16(Ag1 + kt + 32, (char*)As[cur ^ 1] + lo1);
            gload_lds16(Bg0 + kt + 32, (char*)Bs[cur ^ 1] + lo0);
            gload_lds16(Bg1 + kt + 32, (char*)Bs[cur ^ 1] + lo1);
        }

        half8 af[4], bf[4];
#pragma unroll
        for (int i = 0; i < 4; i++)
            af[i] = *(half8*)&As[cur][(wrow + i * 16 + l15) * 32 + quad * 8];
#pragma unroll
        for (int j = 0; j < 4; j++)
            bf[j] = *(half8*)&Bs[cur][(wcol + j * 16 + l15) * 32 + quad * 8];
#pragma unroll
        for (int i = 0; i < 4; i++)
#pragma unroll
            for (int j = 0; j < 4; j++)
                acc[i][j] = mfma16(af[i], bf[j], acc[i][j]);

        __syncthreads();
    }

#pragma unroll
    for (int j = 0; j < 4; j++) {
        int col = n0 + wcol + j * 16 + l15;
        float bv = bias[col];
#pragma unroll
        for (int i = 0; i < 4; i++) {
#pragma unroll
            for (int r = 0; r < 4; r++) {
                int row = m0 + wrow + i * 16 + quad * 4 + r;
                C[(size_t)row * N + col] = acc[i][j][r] + bv;
            }
        }
    }
}

// ---------------- fused cosine attention (32x32 MFMA, in-register softmax) ----------------
// grid: (L/128, B*H). 256 thr = 4 waves; wave w owns queries w*32..w*32+31.
// Swapped QK^T: st = mfma32(Kfrag, Qfrag) -> lane holds scores for q = lane&31,
// k rows crow(r,hi) = (r&3)+8*(r>>2)+4*hi. cvt_pkrtz + permlane32_swap builds the
// PV A-fragment entirely in registers (no P LDS round-trip).
// K/V double-buffered in LDS with next-tile prefetch (one barrier per tile).
__global__ __launch_bounds__(256) void attn_k(const _Float16* __restrict__ Q,
                                              const _Float16* __restrict__ K,
                                              const _Float16* __restrict__ VtG,
                                              _Float16* __restrict__ Mg) {
    __shared__ _Float16 Ks[2][64 * 64];
    __shared__ _Float16 Vt[2][64 * 64];
    __shared__ float lsum[128];

    const float C2 = 20.60992915555662f;  // log2(e)/0.07
    const float OFF = 6.0f;

    int tid = threadIdx.x, wave = tid >> 6, lane = tid & 63;
    int l31 = lane & 31, hi = lane >> 5;
    int bh = blockIdx.y;
    int b = bh >> 4, h = bh & 15;
    int q0 = blockIdx.x * 128;
    size_t rowBase = (size_t)b * LL;
    int colBase = h * 64;
    int wq = wave * 32;
    int xorv = l31 & 7;

    // ---- Q fragments: row = q = l31, dh = d*16 + hi*8 + j (held whole kernel)
    half8 qf[4];
    const _Float16* qp = Q + (rowBase + q0 + wq + l31) * DD + colBase + hi * 8;
#pragma unroll
    for (int d = 0; d < 4; d++) qf[d] = *(const half8*)(qp + d * 16);

    // ---- staging: linear LDS dest, pre-swizzled global source (chunk ^= row&7)
    const _Float16* kg[2];
    const _Float16* vg[2];
    int ldso[2];
#pragma unroll
    for (int p = 0; p < 2; p++) {
        int s = p * 256 + tid;
        int r = s >> 3, cp = s & 7;
        int cs = cp ^ (r & 7);
        kg[p] = K + (rowBase + r) * DD + colBase + cs * 8;
        vg[p] = VtG + ((size_t)bh * 64 + r) * LL + cs * 8;
        ldso[p] = s * 16;
    }

    floatx16 oacc[2] = {};
    float fsum = 0.f;

    // prologue: stage tile 0 into buf 0
    gload_lds16(kg[0], (char*)Ks[0] + ldso[0]);
    gload_lds16(kg[1], (char*)Ks[0] + ldso[1]);
    gload_lds16(vg[0], (char*)Vt[0] + ldso[0]);
    gload_lds16(vg[1], (char*)Vt[0] + ldso[1]);
    kg[0] += 64 * DD; kg[1] += 64 * DD; vg[0] += 64; vg[1] += 64;
    __syncthreads();

#pragma unroll 2
    for (int kt = 0; kt < LL / 64; kt++) {
        int cur = kt & 1;
        // prefetch next tile into other buffer (flies during compute below)
        if (kt + 1 < LL / 64) {
            gload_lds16(kg[0], (char*)Ks[cur ^ 1] + ldso[0]);
            gload_lds16(kg[1], (char*)Ks[cur ^ 1] + ldso[1]);
            gload_lds16(vg[0], (char*)Vt[cur ^ 1] + ldso[0]);
            gload_lds16(vg[1], (char*)Vt[cur ^ 1] + ldso[1]);
            kg[0] += 64 * DD; kg[1] += 64 * DD; vg[0] += 64; vg[1] += 64;
        }
        const char* kb_ = (const char*)Ks[cur];
        const char* vb_ = (const char*)Vt[cur];

#pragma unroll
        for (int c = 0; c < 2; c++) {  // two 32-k blocks per tile
            // ---- QK^T: st = K_block * Q^T  (col = q = l31, row = k = crow(r,hi))
            floatx16 st = {};
            __builtin_amdgcn_s_setprio(1);
#pragma unroll
            for (int d = 0; d < 4; d++) {
                half8 kf = *(const half8*)(kb_ + c * 4096 + l31 * 128 +
                                           (((d * 2 + hi) ^ xorv) * 16));
                st = mfma32(kf, qf[d], st);
            }
            __builtin_amdgcn_s_setprio(0);

            // ---- exp (fixed offset; scores bounded by 1/tau after l2norm)
            float e[16];
#pragma unroll
            for (int r = 0; r < 16; r++)
                e[r] = __builtin_amdgcn_exp2f(st[r] * C2 - OFF);

            // tree sum (16 adds)
            float s0 = (e[0] + e[1]) + (e[2] + e[3]);
            float s1 = (e[4] + e[5]) + (e[6] + e[7]);
            float s2 = (e[8] + e[9]) + (e[10] + e[11]);
            float s3 = (e[12] + e[13]) + (e[14] + e[15]);
            fsum += (s0 + s1) + (s2 + s3);

            // ---- pack to fp16 + in-register transpose: per 16-k slice,
            // swap(pk(e0,e1), pk(e4,e5)) and swap(pk(e2,e3), pk(e6,e7));
            // dword order [a,c,b,d] gives natural k-order A-fragment:
            // hi=0 -> k 0..7, hi=1 -> k 8..15.
            half8 pf[2];
#pragma unroll
            for (int sl = 0; sl < 2; sl++) {
                int bse = sl * 8;
                unsigned a = pkh(e[bse + 0], e[bse + 1]);
                unsigned cc = pkh(e[bse + 2], e[bse + 3]);
                unsigned bb = pkh(e[bse + 4], e[bse + 5]);
                unsigned dd = pkh(e[bse + 6], e[bse + 7]);
                auto r1 = __builtin_amdgcn_permlane32_swap(a, bb, false, false);
                auto r2 = __builtin_amdgcn_permlane32_swap(cc, dd, false, false);
                uint4v u;
                u[0] = (unsigned)r1[0]; u[1] = (unsigned)r2[0];
                u[2] = (unsigned)r1[1]; u[3] = (unsigned)r2[1];
                pf[sl] = __builtin_bit_cast(half8, u);
            }

            // ---- PV partial: oacc[jb] += P_slice * V_slice
            __builtin_amdgcn_s_setprio(1);
#pragma unroll
            for (int jb = 0; jb < 2; jb++) {
#pragma unroll
                for (int sl = 0; sl < 2; sl++) {
                    half8 vf = *(const half8*)(vb_ + jb * 4096 + l31 * 128 +
                                               (((c * 4 + sl * 2 + hi) ^ xorv) * 16));
                    oacc[jb] = mfma32(pf[sl], vf, oacc[jb]);
                }
            }
            __builtin_amdgcn_s_setprio(0);
        }

        __syncthreads();  // compiler drains vmcnt before s_barrier -> next buffer ready
    }

    // ---- epilogue: combine hi-halves of row sums, normalize, store
    fsum += __shfl_xor(fsum, 32);
    lsum[wq + l31] = fsum;
    __syncthreads();

    float inv[16];
#pragma unroll
    for (int r = 0; r < 16; r++) {
        int crow = (r & 3) + 8 * (r >> 2) + 4 * hi;
        inv[r] = 1.0f / lsum[wq + crow];
    }

    _Float16* mp = Mg + (rowBase + q0 + wq) * DD + colBase + l31;
#pragma unroll
    for (int jb = 0; jb < 2; jb++) {
#pragma unroll
        for (int r = 0; r < 16; r++) {
            int crow = (r & 3) + 8 * (r >> 2) + 4 * hi;
            mp[(size_t)crow * DD + jb * 32] = (_Float16)(oacc[jb][r] * inv[r]);
        }
    }
}

// ---------------- launch ----------------
extern "C" void kernel_launch(void* const* d_in, const int* in_sizes, int n_in,
                              void* d_out, int out_size, void* d_ws, size_t ws_size,
                              hipStream_t stream) {
    (void)in_sizes; (void)n_in; (void)out_size; (void)ws_size;
    const float* q  = (const float*)d_in[0];
    const float* k  = (const float*)d_in[1];
    const float* v  = (const float*)d_in[2];
    const float* Wq = (const float*)d_in[3];
    const float* bq = (const float*)d_in[4];
    const float* Wk = (const float*)d_in[5];
    const float* bk = (const float*)d_in[6];
    const float* Wv = (const float*)d_in[7];
    const float* bv = (const float*)d_in[8];
    const float* Wo = (const float*)d_in[9];
    const float* bo = (const float*)d_in[10];

    const size_t NQKV = (size_t)MM * DD;  // 8388608
    const size_t NW = (size_t)DD * DD;    // 1048576

    _Float16* q16  = (_Float16*)d_ws;
    _Float16* k16  = q16 + NQKV;
    _Float16* v16  = k16 + NQKV;
    _Float16* wq16 = v16 + NQKV;
    _Float16* wk16 = wq16 + NW;
    _Float16* wv16 = wk16 + NW;
    _Float16* wo16 = wv16 + NW;
    _Float16* Qp   = wo16 + NW;
    _Float16* Kp   = Qp + NQKV;
    _Float16* VtG  = Kp + NQKV;
    _Float16* Mg   = VtG + NQKV;
    (void)k16; (void)v16;

    // one fused convert: 3*8192 + 4*1024 blocks
    cvt_all<<<dim3(3 * 8192 + 4 * 1024), dim3(256), 0, stream>>>(q, k, v, Wq, Wk, Wv, Wo, q16);

    // fused QKV projection (+l2norm on Q/K, transposed V); A = q16/k16/v16 by block
    gemm_qkv<<<dim3(24, MM / 128), dim3(256), 0, stream>>>(q16, wq16, wk16, wv16,
                                                           bq, bk, bv, Qp, Kp, VtG);

    // fused attention
    attn_k<<<dim3(LL / 128, BB * NH), dim3(256), 0, stream>>>(Qp, Kp, VtG, Mg);

    // output projection -> fp32 d_out
    gemm_out<<<dim3(1024 / 128, MM / 128), dim3(256), 0, stream>>>(Mg, wo16, bo, (float*)d_out);
}